// Round 1
// baseline (8849.780 us; speedup 1.0000x reference)
//
#include <hip/hip_runtime.h>
#include <hip/hip_bf16.h>

#define N_NODES 100000
#define N_EDGES 3200000
#define N_GRAPHS 100
#define DIM 64
#define NCLS 10
#define EPS 0.1f
#define SLOPE 0.01f

__device__ __forceinline__ float lrelu(float v) {
    return v >= 0.f ? v : SLOPE * v;
}

// ---- copy x -> Y (float4) ----
__global__ void copy_kernel(const float* __restrict__ x, float* __restrict__ Y, int n4) {
    int i = blockIdx.x * blockDim.x + threadIdx.x;
    if (i < n4) ((float4*)Y)[i] = ((const float4*)x)[i];
}

// ---- edge scatter: agg[dst] += Y[src], 16 threads per edge ----
__global__ void __launch_bounds__(256) scatter_kernel(const float* __restrict__ Y,
                                                      const int* __restrict__ src,
                                                      const int* __restrict__ dst,
                                                      float* __restrict__ agg, int E) {
    int t = blockIdx.x * blockDim.x + threadIdx.x;
    int e = t >> 4;
    if (e >= E) return;
    int f4 = t & 15;
    int s = src[e];
    int d = dst[e];
    float4 v = ((const float4*)(Y + (size_t)s * DIM))[f4];
    float* ap = agg + (size_t)d * DIM + f4 * 4;
    atomicAdd(ap + 0, v.x);
    atomicAdd(ap + 1, v.y);
    atomicAdd(ap + 2, v.z);
    atomicAdd(ap + 3, v.w);
}

// ---- per-row MLP: Y = lrelu(lrelu(lrelu((1+eps)Y + agg)@W1+b1)@W2+b2)  in-place ----
#define ROWS_PER_BLOCK 64
__global__ void __launch_bounds__(256) mlp_kernel(float* __restrict__ Y,
                                                  const float* __restrict__ agg,
                                                  const float* __restrict__ W1,
                                                  const float* __restrict__ b1,
                                                  const float* __restrict__ W2,
                                                  const float* __restrict__ b2, int N) {
    __shared__ float sW1[DIM * DIM];
    __shared__ float sW2[DIM * DIM];
    __shared__ float sb1[DIM];
    __shared__ float sb2[DIM];
    int tid = threadIdx.x;
    for (int i = tid; i < DIM * DIM; i += 256) {
        sW1[i] = W1[i];
        sW2[i] = W2[i];
    }
    if (tid < DIM) { sb1[tid] = b1[tid]; sb2[tid] = b2[tid]; }
    __syncthreads();

    int wave = tid >> 6, lane = tid & 63;
    int base = blockIdx.x * ROWS_PER_BLOCK;
    for (int r = wave; r < ROWS_PER_BLOCK; r += 4) {
        int row = base + r;
        if (row >= N) break;   // no barriers below; per-wave independent
        size_t off = (size_t)row * DIM + lane;
        float h = (1.0f + EPS) * Y[off] + agg[off];
        float acc = sb1[lane];
#pragma unroll
        for (int k = 0; k < DIM; ++k)
            acc += __shfl(h, k) * sW1[k * DIM + lane];
        acc = lrelu(acc);
        float acc2 = sb2[lane];
#pragma unroll
        for (int k = 0; k < DIM; ++k)
            acc2 += __shfl(acc, k) * sW2[k * DIM + lane];
        float y = lrelu(lrelu(acc2));  // inner lrelu + outer lrelu of the round
        Y[off] = y;
    }
}

// ---- per-graph readout with LDS staging ----
__global__ void __launch_bounds__(256) readout_kernel(const float* __restrict__ Y,
                                                      const int* __restrict__ gid,
                                                      float* __restrict__ em, int N) {
    __shared__ float sAcc[N_GRAPHS * DIM];
    for (int i = threadIdx.x; i < N_GRAPHS * DIM; i += 256) sAcc[i] = 0.f;
    __syncthreads();
    int lane = threadIdx.x & 63, wave = threadIdx.x >> 6;
    int stride = gridDim.x * 4;
    for (int n = blockIdx.x * 4 + wave; n < N; n += stride) {
        int g = gid[n];
        atomicAdd(&sAcc[g * DIM + lane], Y[(size_t)n * DIM + lane]);
    }
    __syncthreads();
    for (int i = threadIdx.x; i < N_GRAPHS * DIM; i += 256) atomicAdd(&em[i], sAcc[i]);
}

// ---- classifier: out = lrelu(em@W1+b1) @ W2 + b2 ----
__global__ void __launch_bounds__(256) cls_kernel(const float* __restrict__ em,
                                                  const float* __restrict__ W1,
                                                  const float* __restrict__ b1,
                                                  const float* __restrict__ W2,
                                                  const float* __restrict__ b2,
                                                  float* __restrict__ out) {
    __shared__ float sT[N_GRAPHS * DIM];
    __shared__ float sW1[DIM * DIM];
    for (int i = threadIdx.x; i < DIM * DIM; i += 256) sW1[i] = W1[i];
    __syncthreads();
    for (int i = threadIdx.x; i < N_GRAPHS * DIM; i += 256) {
        int g = i >> 6, j = i & 63;
        float acc = b1[j];
#pragma unroll
        for (int k = 0; k < DIM; ++k) acc += em[g * DIM + k] * sW1[k * DIM + j];
        sT[i] = lrelu(acc);
    }
    __syncthreads();
    for (int i = threadIdx.x; i < N_GRAPHS * NCLS; i += 256) {
        int g = i / NCLS, c = i % NCLS;
        float acc = b2[c];
#pragma unroll
        for (int k = 0; k < DIM; ++k) acc += sT[g * DIM + k] * W2[k * NCLS + c];
        out[i] = acc;
    }
}

extern "C" void kernel_launch(void* const* d_in, const int* in_sizes, int n_in,
                              void* d_out, int out_size, void* d_ws, size_t ws_size,
                              hipStream_t stream) {
    const float* x        = (const float*)d_in[0];
    const int*   src      = (const int*)d_in[1];
    const int*   dst      = (const int*)d_in[2];
    const int*   gid      = (const int*)d_in[3];
    const float* mlp0_W1  = (const float*)d_in[4];
    const float* mlp0_b1  = (const float*)d_in[5];
    const float* mlp0_W2  = (const float*)d_in[6];
    const float* mlp0_b2  = (const float*)d_in[7];
    const float* mlps_W1  = (const float*)d_in[8];   // [2,64,64]
    const float* mlps_b1  = (const float*)d_in[9];   // [2,64]
    const float* mlps_W2  = (const float*)d_in[10];
    const float* mlps_b2  = (const float*)d_in[11];
    const float* cls_W1   = (const float*)d_in[12];
    const float* cls_b1   = (const float*)d_in[13];
    const float* cls_W2   = (const float*)d_in[14];
    const float* cls_b2   = (const float*)d_in[15];
    float* out = (float*)d_out;

    float* Y   = (float*)d_ws;                           // N*64 floats
    float* agg = Y + (size_t)N_NODES * DIM;              // N*64 floats
    float* em  = agg + (size_t)N_NODES * DIM;            // 100*64 floats

    // copy x -> Y
    {
        int n4 = N_NODES * DIM / 4;
        copy_kernel<<<(n4 + 255) / 256, 256, 0, stream>>>(x, Y, n4);
    }

    for (int j = 0; j < 3; ++j) {
        hipMemsetAsync(agg, 0, (size_t)N_NODES * DIM * sizeof(float), stream);
        {
            long long threads = (long long)N_EDGES * 16;
            int blocks = (int)((threads + 255) / 256);
            scatter_kernel<<<blocks, 256, 0, stream>>>(Y, src, dst, agg, N_EDGES);
        }
        const float *W1, *b1, *W2, *b2;
        if (j == 0) { W1 = mlp0_W1; b1 = mlp0_b1; W2 = mlp0_W2; b2 = mlp0_b2; }
        else {
            W1 = mlps_W1 + (size_t)(j - 1) * DIM * DIM;
            b1 = mlps_b1 + (size_t)(j - 1) * DIM;
            W2 = mlps_W2 + (size_t)(j - 1) * DIM * DIM;
            b2 = mlps_b2 + (size_t)(j - 1) * DIM;
        }
        int blocks = (N_NODES + ROWS_PER_BLOCK - 1) / ROWS_PER_BLOCK;
        mlp_kernel<<<blocks, 256, 0, stream>>>(Y, agg, W1, b1, W2, b2, N_NODES);
    }

    hipMemsetAsync(em, 0, (size_t)N_GRAPHS * DIM * sizeof(float), stream);
    readout_kernel<<<128, 256, 0, stream>>>(Y, gid, em, N_NODES);
    cls_kernel<<<1, 256, 0, stream>>>(em, cls_W1, cls_b1, cls_W2, cls_b2, out);
}

// Round 2
// 1763.003 us; speedup vs baseline: 5.0197x; 5.0197x over previous
//
#include <hip/hip_runtime.h>
#include <hip/hip_bf16.h>

#define N_NODES 100000
#define N_EDGES 3200000
#define N_GRAPHS 100
#define DIM 64
#define NCLS 10
#define EPS 0.1f
#define SLOPE 0.01f

__device__ __forceinline__ float lrelu(float v) {
    return v >= 0.f ? v : SLOPE * v;
}

// ======================= CSR build =======================
__global__ void __launch_bounds__(256) hist_kernel(const int* __restrict__ dst,
                                                   int* __restrict__ counts, int E) {
    int i = blockIdx.x * 256 + threadIdx.x;
    if (i < E) atomicAdd(&counts[dst[i]], 1);
}

#define SCAN_T 1024
__global__ void __launch_bounds__(SCAN_T) scan_kernel(const int* __restrict__ counts,
                                                      int* __restrict__ rowptr,
                                                      int* __restrict__ cursor, int N) {
    __shared__ int sS[SCAN_T];
    int t = threadIdx.x;
    int chunk = (N + SCAN_T - 1) / SCAN_T;
    int lo = t * chunk, hi = lo + chunk;
    if (hi > N) hi = N;
    if (lo > N) lo = N;
    int s = 0;
    for (int i = lo; i < hi; ++i) s += counts[i];
    sS[t] = s;
    __syncthreads();
    for (int off = 1; off < SCAN_T; off <<= 1) {
        int v = (t >= off) ? sS[t - off] : 0;
        __syncthreads();
        sS[t] += v;
        __syncthreads();
    }
    int run = sS[t] - s;  // exclusive base for this chunk
    for (int i = lo; i < hi; ++i) {
        rowptr[i] = run;
        cursor[i] = run;
        run += counts[i];
    }
    if (t == SCAN_T - 1) rowptr[N] = sS[SCAN_T - 1];
}

__global__ void __launch_bounds__(256) fill_kernel(const int* __restrict__ src,
                                                   const int* __restrict__ dst,
                                                   int* __restrict__ cursor,
                                                   int* __restrict__ ssrc, int E) {
    int e = blockIdx.x * 256 + threadIdx.x;
    if (e < E) {
        int p = atomicAdd(&cursor[dst[e]], 1);
        ssrc[p] = src[e];
    }
}

// ======================= fused gather + MLP round =======================
// wave per node (grid-stride): agg = (1+eps)*Yin[n] + sum_{e in in(n)} Yin[ssrc[e]]
// then Yout[n] = lrelu(lrelu(lrelu(agg@W1+b1)@W2+b2))
__global__ void __launch_bounds__(256) round_kernel(const float* __restrict__ Yin,
                                                    float* __restrict__ Yout,
                                                    const int* __restrict__ rowptr,
                                                    const int* __restrict__ ssrc,
                                                    const float* __restrict__ W1,
                                                    const float* __restrict__ b1,
                                                    const float* __restrict__ W2,
                                                    const float* __restrict__ b2, int N) {
    __shared__ float sW1[DIM * DIM];
    __shared__ float sW2[DIM * DIM];
    __shared__ float sb1[DIM];
    __shared__ float sb2[DIM];
    int tid = threadIdx.x;
    for (int i = tid; i < DIM * DIM; i += 256) {
        sW1[i] = W1[i];
        sW2[i] = W2[i];
    }
    if (tid < DIM) { sb1[tid] = b1[tid]; sb2[tid] = b2[tid]; }
    __syncthreads();

    int wave = tid >> 6, lane = tid & 63;
    int stride = gridDim.x * 4;
    for (int n = blockIdx.x * 4 + wave; n < N; n += stride) {
        int beg = rowptr[n], end = rowptr[n + 1];
        float a0 = (1.0f + EPS) * Yin[(size_t)n * DIM + lane];
        float a1 = 0.f, a2 = 0.f, a3 = 0.f;
        int e = beg;
        for (; e + 4 <= end; e += 4) {
            int s0 = ssrc[e], s1 = ssrc[e + 1], s2 = ssrc[e + 2], s3 = ssrc[e + 3];
            a0 += Yin[(size_t)s0 * DIM + lane];
            a1 += Yin[(size_t)s1 * DIM + lane];
            a2 += Yin[(size_t)s2 * DIM + lane];
            a3 += Yin[(size_t)s3 * DIM + lane];
        }
        for (; e < end; ++e) a0 += Yin[(size_t)ssrc[e] * DIM + lane];
        float h = (a0 + a1) + (a2 + a3);

        float c1 = sb1[lane];
#pragma unroll
        for (int k = 0; k < DIM; ++k) c1 += __shfl(h, k) * sW1[k * DIM + lane];
        c1 = lrelu(c1);
        float c2 = sb2[lane];
#pragma unroll
        for (int k = 0; k < DIM; ++k) c2 += __shfl(c1, k) * sW2[k * DIM + lane];
        Yout[(size_t)n * DIM + lane] = lrelu(lrelu(c2));
    }
}

// ======================= fallback (atomic scatter) =======================
__global__ void copy_kernel(const float* __restrict__ x, float* __restrict__ Y, int n4) {
    int i = blockIdx.x * blockDim.x + threadIdx.x;
    if (i < n4) ((float4*)Y)[i] = ((const float4*)x)[i];
}

__global__ void __launch_bounds__(256) scatter_kernel(const float* __restrict__ Y,
                                                      const int* __restrict__ src,
                                                      const int* __restrict__ dst,
                                                      float* __restrict__ agg, int E) {
    int t = blockIdx.x * blockDim.x + threadIdx.x;
    int e = t >> 4;
    if (e >= E) return;
    int f4 = t & 15;
    int s = src[e];
    int d = dst[e];
    float4 v = ((const float4*)(Y + (size_t)s * DIM))[f4];
    float* ap = agg + (size_t)d * DIM + f4 * 4;
    atomicAdd(ap + 0, v.x);
    atomicAdd(ap + 1, v.y);
    atomicAdd(ap + 2, v.z);
    atomicAdd(ap + 3, v.w);
}

__global__ void __launch_bounds__(256) mlp_kernel(float* __restrict__ Y,
                                                  const float* __restrict__ agg,
                                                  const float* __restrict__ W1,
                                                  const float* __restrict__ b1,
                                                  const float* __restrict__ W2,
                                                  const float* __restrict__ b2, int N) {
    __shared__ float sW1[DIM * DIM];
    __shared__ float sW2[DIM * DIM];
    __shared__ float sb1[DIM];
    __shared__ float sb2[DIM];
    int tid = threadIdx.x;
    for (int i = tid; i < DIM * DIM; i += 256) {
        sW1[i] = W1[i];
        sW2[i] = W2[i];
    }
    if (tid < DIM) { sb1[tid] = b1[tid]; sb2[tid] = b2[tid]; }
    __syncthreads();
    int wave = tid >> 6, lane = tid & 63;
    int base = blockIdx.x * 64;
    for (int r = wave; r < 64; r += 4) {
        int row = base + r;
        if (row >= N) break;
        size_t off = (size_t)row * DIM + lane;
        float h = (1.0f + EPS) * Y[off] + agg[off];
        float acc = sb1[lane];
#pragma unroll
        for (int k = 0; k < DIM; ++k) acc += __shfl(h, k) * sW1[k * DIM + lane];
        acc = lrelu(acc);
        float acc2 = sb2[lane];
#pragma unroll
        for (int k = 0; k < DIM; ++k) acc2 += __shfl(acc, k) * sW2[k * DIM + lane];
        Y[off] = lrelu(lrelu(acc2));
    }
}

// ======================= readout + classifier =======================
__global__ void __launch_bounds__(256) readout_kernel(const float* __restrict__ Y,
                                                      const int* __restrict__ gid,
                                                      float* __restrict__ em, int N) {
    __shared__ float sAcc[N_GRAPHS * DIM];
    for (int i = threadIdx.x; i < N_GRAPHS * DIM; i += 256) sAcc[i] = 0.f;
    __syncthreads();
    int lane = threadIdx.x & 63, wave = threadIdx.x >> 6;
    int stride = gridDim.x * 4;
    for (int n = blockIdx.x * 4 + wave; n < N; n += stride) {
        int g = gid[n];
        atomicAdd(&sAcc[g * DIM + lane], Y[(size_t)n * DIM + lane]);
    }
    __syncthreads();
    for (int i = threadIdx.x; i < N_GRAPHS * DIM; i += 256) atomicAdd(&em[i], sAcc[i]);
}

__global__ void __launch_bounds__(256) cls_kernel(const float* __restrict__ em,
                                                  const float* __restrict__ W1,
                                                  const float* __restrict__ b1,
                                                  const float* __restrict__ W2,
                                                  const float* __restrict__ b2,
                                                  float* __restrict__ out) {
    __shared__ float sT[N_GRAPHS * DIM];
    __shared__ float sW1[DIM * DIM];
    for (int i = threadIdx.x; i < DIM * DIM; i += 256) sW1[i] = W1[i];
    __syncthreads();
    for (int i = threadIdx.x; i < N_GRAPHS * DIM; i += 256) {
        int g = i >> 6, j = i & 63;
        float acc = b1[j];
#pragma unroll
        for (int k = 0; k < DIM; ++k) acc += em[g * DIM + k] * sW1[k * DIM + j];
        sT[i] = lrelu(acc);
    }
    __syncthreads();
    for (int i = threadIdx.x; i < N_GRAPHS * NCLS; i += 256) {
        int g = i / NCLS, c = i % NCLS;
        float acc = b2[c];
#pragma unroll
        for (int k = 0; k < DIM; ++k) acc += sT[g * DIM + k] * W2[k * NCLS + c];
        out[i] = acc;
    }
}

extern "C" void kernel_launch(void* const* d_in, const int* in_sizes, int n_in,
                              void* d_out, int out_size, void* d_ws, size_t ws_size,
                              hipStream_t stream) {
    const float* x       = (const float*)d_in[0];
    const int*   src     = (const int*)d_in[1];
    const int*   dst     = (const int*)d_in[2];
    const int*   gid     = (const int*)d_in[3];
    const float* mlp0_W1 = (const float*)d_in[4];
    const float* mlp0_b1 = (const float*)d_in[5];
    const float* mlp0_W2 = (const float*)d_in[6];
    const float* mlp0_b2 = (const float*)d_in[7];
    const float* mlps_W1 = (const float*)d_in[8];
    const float* mlps_b1 = (const float*)d_in[9];
    const float* mlps_W2 = (const float*)d_in[10];
    const float* mlps_b2 = (const float*)d_in[11];
    const float* cls_W1  = (const float*)d_in[12];
    const float* cls_b1  = (const float*)d_in[13];
    const float* cls_W2  = (const float*)d_in[14];
    const float* cls_b2  = (const float*)d_in[15];
    float* out = (float*)d_out;

    const size_t szY  = (size_t)N_NODES * DIM * sizeof(float);    // 25.6 MB
    const size_t szEm = (size_t)N_GRAPHS * DIM * sizeof(float);
    const size_t szRp = (size_t)(N_NODES + 1) * sizeof(int);
    const size_t szN  = (size_t)N_NODES * sizeof(int);
    const size_t szE  = (size_t)N_EDGES * sizeof(int);
    const size_t need = 2 * szY + szEm + szRp + 2 * szN + szE;    // ~65.2 MB

    const float* roundW1[3] = {mlp0_W1, mlps_W1, mlps_W1 + DIM * DIM};
    const float* roundB1[3] = {mlp0_b1, mlps_b1, mlps_b1 + DIM};
    const float* roundW2[3] = {mlp0_W2, mlps_W2, mlps_W2 + DIM * DIM};
    const float* roundB2[3] = {mlp0_b2, mlps_b2, mlps_b2 + DIM};

    if (ws_size >= need) {
        char* w = (char*)d_ws;
        float* Ya     = (float*)w;            w += szY;
        float* Yb     = (float*)w;            w += szY;
        float* em     = (float*)w;            w += szEm;
        int*   rowptr = (int*)w;              w += szRp;
        int*   cursor = (int*)w;              w += szN;
        int*   counts = (int*)w;              w += szN;
        int*   ssrc   = (int*)w;              w += szE;

        // --- CSR build ---
        hipMemsetAsync(counts, 0, szN, stream);
        int eBlocks = (N_EDGES + 255) / 256;
        hist_kernel<<<eBlocks, 256, 0, stream>>>(dst, counts, N_EDGES);
        scan_kernel<<<1, SCAN_T, 0, stream>>>(counts, rowptr, cursor, N_NODES);
        fill_kernel<<<eBlocks, 256, 0, stream>>>(src, dst, cursor, ssrc, N_EDGES);

        // --- rounds: x -> Ya -> Yb -> Ya ---
        const float* Yin[3]  = {x, Ya, Yb};
        float*       Yout[3] = {Ya, Yb, Ya};
        for (int j = 0; j < 3; ++j) {
            round_kernel<<<1024, 256, 0, stream>>>(Yin[j], Yout[j], rowptr, ssrc,
                                                   roundW1[j], roundB1[j],
                                                   roundW2[j], roundB2[j], N_NODES);
        }

        hipMemsetAsync(em, 0, szEm, stream);
        readout_kernel<<<128, 256, 0, stream>>>(Ya, gid, em, N_NODES);
        cls_kernel<<<1, 256, 0, stream>>>(em, cls_W1, cls_b1, cls_W2, cls_b2, out);
    } else {
        // fallback: original atomic-scatter path (needs 2*szY + szEm)
        float* Y   = (float*)d_ws;
        float* agg = Y + (size_t)N_NODES * DIM;
        float* em  = agg + (size_t)N_NODES * DIM;
        int n4 = N_NODES * DIM / 4;
        copy_kernel<<<(n4 + 255) / 256, 256, 0, stream>>>(x, Y, n4);
        for (int j = 0; j < 3; ++j) {
            hipMemsetAsync(agg, 0, szY, stream);
            long long threads = (long long)N_EDGES * 16;
            int blocks = (int)((threads + 255) / 256);
            scatter_kernel<<<blocks, 256, 0, stream>>>(Y, src, dst, agg, N_EDGES);
            int mb = (N_NODES + 63) / 64;
            mlp_kernel<<<mb, 256, 0, stream>>>(Y, agg, roundW1[j], roundB1[j],
                                               roundW2[j], roundB2[j], N_NODES);
        }
        hipMemsetAsync(em, 0, szEm, stream);
        readout_kernel<<<128, 256, 0, stream>>>(Y, gid, em, N_NODES);
        cls_kernel<<<1, 256, 0, stream>>>(em, cls_W1, cls_b1, cls_W2, cls_b2, out);
    }
}

// Round 3
// 1566.722 us; speedup vs baseline: 5.6486x; 1.1253x over previous
//
#include <hip/hip_runtime.h>
#include <hip/hip_bf16.h>

#define N_NODES 100000
#define N_EDGES 3200000
#define N_GRAPHS 100
#define DIM 64
#define NCLS 10
#define EPS 0.1f
#define SLOPE 0.01f

__device__ __forceinline__ float lrelu(float v) {
    return v >= 0.f ? v : SLOPE * v;
}

// ======================= CSR build =======================
__global__ void __launch_bounds__(256) hist_kernel(const int* __restrict__ dst,
                                                   int* __restrict__ counts, int E) {
    int i = blockIdx.x * 256 + threadIdx.x;
    if (i < E) atomicAdd(&counts[dst[i]], 1);
}

#define SCAN_T 1024
__global__ void __launch_bounds__(SCAN_T) scan_kernel(const int* __restrict__ counts,
                                                      int* __restrict__ rowptr,
                                                      int* __restrict__ cursor, int N) {
    __shared__ int sS[SCAN_T];
    int t = threadIdx.x;
    int chunk = (N + SCAN_T - 1) / SCAN_T;
    int lo = t * chunk, hi = lo + chunk;
    if (hi > N) hi = N;
    if (lo > N) lo = N;
    int s = 0;
    for (int i = lo; i < hi; ++i) s += counts[i];
    sS[t] = s;
    __syncthreads();
    for (int off = 1; off < SCAN_T; off <<= 1) {
        int v = (t >= off) ? sS[t - off] : 0;
        __syncthreads();
        sS[t] += v;
        __syncthreads();
    }
    int run = sS[t] - s;  // exclusive base for this chunk
    for (int i = lo; i < hi; ++i) {
        rowptr[i] = run;
        cursor[i] = run;
        run += counts[i];
    }
    if (t == SCAN_T - 1) rowptr[N] = sS[SCAN_T - 1];
}

__global__ void __launch_bounds__(256) fill_kernel(const int* __restrict__ src,
                                                   const int* __restrict__ dst,
                                                   int* __restrict__ cursor,
                                                   int* __restrict__ ssrc, int E) {
    int e = blockIdx.x * 256 + threadIdx.x;
    if (e < E) {
        int p = atomicAdd(&cursor[dst[e]], 1);
        ssrc[p] = src[e];
    }
}

// ======================= fused gather + MLP round =======================
// wave per node (grid-stride). Lane partition: sub = lane>>4 (row slot 0..3),
// seg = lane&15 (float4 feature segment). One VMEM instr gathers 4 rows.
__global__ void __launch_bounds__(256) round_kernel(const float* __restrict__ Yin,
                                                    float* __restrict__ Yout,
                                                    const int* __restrict__ rowptr,
                                                    const int* __restrict__ ssrc,
                                                    const float* __restrict__ W1,
                                                    const float* __restrict__ b1,
                                                    const float* __restrict__ W2,
                                                    const float* __restrict__ b2, int N) {
    __shared__ float sW1[DIM * DIM];
    __shared__ float sW2[DIM * DIM];
    __shared__ float sb1[DIM];
    __shared__ float sb2[DIM];
    int tid = threadIdx.x;
    for (int i = tid; i < DIM * DIM; i += 256) {
        sW1[i] = W1[i];
        sW2[i] = W2[i];
    }
    if (tid < DIM) { sb1[tid] = b1[tid]; sb2[tid] = b2[tid]; }
    __syncthreads();

    const int wave = tid >> 6, lane = tid & 63;
    const int sub = lane >> 4;    // which of 4 rows this lane helps load
    const int seg = lane & 15;    // which float4 segment of the row
    const int stride = gridDim.x * 4;

    for (int n0 = blockIdx.x * 4 + wave; n0 < N; n0 += stride) {
        const int n = __builtin_amdgcn_readfirstlane(n0);   // wave-uniform
        const int beg = rowptr[n];
        const int end = rowptr[n + 1];

        float4 acc = make_float4(0.f, 0.f, 0.f, 0.f);
        if (sub == 0) {  // self term (1+eps)*Yin[n], counted once
            float4 v = ((const float4*)(Yin + (size_t)n * DIM))[seg];
            acc.x = (1.0f + EPS) * v.x;
            acc.y = (1.0f + EPS) * v.y;
            acc.z = (1.0f + EPS) * v.z;
            acc.w = (1.0f + EPS) * v.w;
        }

        for (int base = beg; base < end; base += 64) {
            int rem = end - base;
            int cnt = rem < 64 ? rem : 64;
            int idx = 0;
            if (lane < cnt) idx = ssrc[base + lane];   // 1 coalesced load / 64 edges
            int iters = (cnt + 3) >> 2;
            for (int i = 0; i < iters; ++i) {
                int r = __shfl(idx, i * 4 + sub);
                if (i * 4 + sub < cnt) {
                    float4 v = ((const float4*)(Yin + (size_t)r * DIM))[seg];
                    acc.x += v.x; acc.y += v.y; acc.z += v.z; acc.w += v.w;
                }
            }
        }

        // fold the 4 row-slots: xor over lanes 16 and 32 apart
        acc.x += __shfl_xor(acc.x, 16); acc.y += __shfl_xor(acc.y, 16);
        acc.z += __shfl_xor(acc.z, 16); acc.w += __shfl_xor(acc.w, 16);
        acc.x += __shfl_xor(acc.x, 32); acc.y += __shfl_xor(acc.y, 32);
        acc.z += __shfl_xor(acc.z, 32); acc.w += __shfl_xor(acc.w, 32);
        // every lane now holds h[seg*4 .. seg*4+3]

        float c1 = sb1[lane];
#pragma unroll
        for (int s = 0; s < 16; ++s) {
            float hx = __shfl(acc.x, s);
            float hy = __shfl(acc.y, s);
            float hz = __shfl(acc.z, s);
            float hw = __shfl(acc.w, s);
            c1 += hx * sW1[(4 * s + 0) * DIM + lane];
            c1 += hy * sW1[(4 * s + 1) * DIM + lane];
            c1 += hz * sW1[(4 * s + 2) * DIM + lane];
            c1 += hw * sW1[(4 * s + 3) * DIM + lane];
        }
        c1 = lrelu(c1);
        float c2 = sb2[lane];
#pragma unroll
        for (int k = 0; k < DIM; ++k) c2 += __shfl(c1, k) * sW2[k * DIM + lane];
        Yout[(size_t)n * DIM + lane] = lrelu(lrelu(c2));
    }
}

// ======================= fallback (atomic scatter) =======================
__global__ void copy_kernel(const float* __restrict__ x, float* __restrict__ Y, int n4) {
    int i = blockIdx.x * blockDim.x + threadIdx.x;
    if (i < n4) ((float4*)Y)[i] = ((const float4*)x)[i];
}

__global__ void __launch_bounds__(256) scatter_kernel(const float* __restrict__ Y,
                                                      const int* __restrict__ src,
                                                      const int* __restrict__ dst,
                                                      float* __restrict__ agg, int E) {
    int t = blockIdx.x * blockDim.x + threadIdx.x;
    int e = t >> 4;
    if (e >= E) return;
    int f4 = t & 15;
    int s = src[e];
    int d = dst[e];
    float4 v = ((const float4*)(Y + (size_t)s * DIM))[f4];
    float* ap = agg + (size_t)d * DIM + f4 * 4;
    atomicAdd(ap + 0, v.x);
    atomicAdd(ap + 1, v.y);
    atomicAdd(ap + 2, v.z);
    atomicAdd(ap + 3, v.w);
}

__global__ void __launch_bounds__(256) mlp_kernel(float* __restrict__ Y,
                                                  const float* __restrict__ agg,
                                                  const float* __restrict__ W1,
                                                  const float* __restrict__ b1,
                                                  const float* __restrict__ W2,
                                                  const float* __restrict__ b2, int N) {
    __shared__ float sW1[DIM * DIM];
    __shared__ float sW2[DIM * DIM];
    __shared__ float sb1[DIM];
    __shared__ float sb2[DIM];
    int tid = threadIdx.x;
    for (int i = tid; i < DIM * DIM; i += 256) {
        sW1[i] = W1[i];
        sW2[i] = W2[i];
    }
    if (tid < DIM) { sb1[tid] = b1[tid]; sb2[tid] = b2[tid]; }
    __syncthreads();
    int wave = tid >> 6, lane = tid & 63;
    int base = blockIdx.x * 64;
    for (int r = wave; r < 64; r += 4) {
        int row = base + r;
        if (row >= N) break;
        size_t off = (size_t)row * DIM + lane;
        float h = (1.0f + EPS) * Y[off] + agg[off];
        float acc = sb1[lane];
#pragma unroll
        for (int k = 0; k < DIM; ++k) acc += __shfl(h, k) * sW1[k * DIM + lane];
        acc = lrelu(acc);
        float acc2 = sb2[lane];
#pragma unroll
        for (int k = 0; k < DIM; ++k) acc2 += __shfl(acc, k) * sW2[k * DIM + lane];
        Y[off] = lrelu(lrelu(acc2));
    }
}

// ======================= readout + classifier =======================
__global__ void __launch_bounds__(256) readout_kernel(const float* __restrict__ Y,
                                                      const int* __restrict__ gid,
                                                      float* __restrict__ em, int N) {
    __shared__ float sAcc[N_GRAPHS * DIM];
    for (int i = threadIdx.x; i < N_GRAPHS * DIM; i += 256) sAcc[i] = 0.f;
    __syncthreads();
    int lane = threadIdx.x & 63, wave = threadIdx.x >> 6;
    int stride = gridDim.x * 4;
    for (int n = blockIdx.x * 4 + wave; n < N; n += stride) {
        int g = gid[n];
        atomicAdd(&sAcc[g * DIM + lane], Y[(size_t)n * DIM + lane]);
    }
    __syncthreads();
    for (int i = threadIdx.x; i < N_GRAPHS * DIM; i += 256) atomicAdd(&em[i], sAcc[i]);
}

__global__ void __launch_bounds__(256) cls_kernel(const float* __restrict__ em,
                                                  const float* __restrict__ W1,
                                                  const float* __restrict__ b1,
                                                  const float* __restrict__ W2,
                                                  const float* __restrict__ b2,
                                                  float* __restrict__ out) {
    __shared__ float sT[N_GRAPHS * DIM];
    __shared__ float sW1[DIM * DIM];
    for (int i = threadIdx.x; i < DIM * DIM; i += 256) sW1[i] = W1[i];
    __syncthreads();
    for (int i = threadIdx.x; i < N_GRAPHS * DIM; i += 256) {
        int g = i >> 6, j = i & 63;
        float acc = b1[j];
#pragma unroll
        for (int k = 0; k < DIM; ++k) acc += em[g * DIM + k] * sW1[k * DIM + j];
        sT[i] = lrelu(acc);
    }
    __syncthreads();
    for (int i = threadIdx.x; i < N_GRAPHS * NCLS; i += 256) {
        int g = i / NCLS, c = i % NCLS;
        float acc = b2[c];
#pragma unroll
        for (int k = 0; k < DIM; ++k) acc += sT[g * DIM + k] * W2[k * NCLS + c];
        out[i] = acc;
    }
}

extern "C" void kernel_launch(void* const* d_in, const int* in_sizes, int n_in,
                              void* d_out, int out_size, void* d_ws, size_t ws_size,
                              hipStream_t stream) {
    const float* x       = (const float*)d_in[0];
    const int*   src     = (const int*)d_in[1];
    const int*   dst     = (const int*)d_in[2];
    const int*   gid     = (const int*)d_in[3];
    const float* mlp0_W1 = (const float*)d_in[4];
    const float* mlp0_b1 = (const float*)d_in[5];
    const float* mlp0_W2 = (const float*)d_in[6];
    const float* mlp0_b2 = (const float*)d_in[7];
    const float* mlps_W1 = (const float*)d_in[8];
    const float* mlps_b1 = (const float*)d_in[9];
    const float* mlps_W2 = (const float*)d_in[10];
    const float* mlps_b2 = (const float*)d_in[11];
    const float* cls_W1  = (const float*)d_in[12];
    const float* cls_b1  = (const float*)d_in[13];
    const float* cls_W2  = (const float*)d_in[14];
    const float* cls_b2  = (const float*)d_in[15];
    float* out = (float*)d_out;

    const size_t szY  = (size_t)N_NODES * DIM * sizeof(float);    // 25.6 MB
    const size_t szEm = (size_t)N_GRAPHS * DIM * sizeof(float);
    const size_t szRp = (size_t)(N_NODES + 1) * sizeof(int);
    const size_t szN  = (size_t)N_NODES * sizeof(int);
    const size_t szE  = (size_t)N_EDGES * sizeof(int);
    const size_t need = 2 * szY + szEm + szRp + 2 * szN + szE;    // ~65.2 MB

    const float* roundW1[3] = {mlp0_W1, mlps_W1, mlps_W1 + DIM * DIM};
    const float* roundB1[3] = {mlp0_b1, mlps_b1, mlps_b1 + DIM};
    const float* roundW2[3] = {mlp0_W2, mlps_W2, mlps_W2 + DIM * DIM};
    const float* roundB2[3] = {mlp0_b2, mlps_b2, mlps_b2 + DIM};

    if (ws_size >= need) {
        char* w = (char*)d_ws;
        float* Ya     = (float*)w;            w += szY;
        float* Yb     = (float*)w;            w += szY;
        float* em     = (float*)w;            w += szEm;
        int*   rowptr = (int*)w;              w += szRp;
        int*   cursor = (int*)w;              w += szN;
        int*   counts = (int*)w;              w += szN;
        int*   ssrc   = (int*)w;              w += szE;

        // --- CSR build ---
        hipMemsetAsync(counts, 0, szN, stream);
        int eBlocks = (N_EDGES + 255) / 256;
        hist_kernel<<<eBlocks, 256, 0, stream>>>(dst, counts, N_EDGES);
        scan_kernel<<<1, SCAN_T, 0, stream>>>(counts, rowptr, cursor, N_NODES);
        fill_kernel<<<eBlocks, 256, 0, stream>>>(src, dst, cursor, ssrc, N_EDGES);

        // --- rounds: x -> Ya -> Yb -> Ya ---
        const float* Yin[3]  = {x, Ya, Yb};
        float*       Yout[3] = {Ya, Yb, Ya};
        for (int j = 0; j < 3; ++j) {
            round_kernel<<<1024, 256, 0, stream>>>(Yin[j], Yout[j], rowptr, ssrc,
                                                   roundW1[j], roundB1[j],
                                                   roundW2[j], roundB2[j], N_NODES);
        }

        hipMemsetAsync(em, 0, szEm, stream);
        readout_kernel<<<128, 256, 0, stream>>>(Ya, gid, em, N_NODES);
        cls_kernel<<<1, 256, 0, stream>>>(em, cls_W1, cls_b1, cls_W2, cls_b2, out);
    } else {
        // fallback: atomic-scatter path (needs 2*szY + szEm)
        float* Y   = (float*)d_ws;
        float* agg = Y + (size_t)N_NODES * DIM;
        float* em  = agg + (size_t)N_NODES * DIM;
        int n4 = N_NODES * DIM / 4;
        copy_kernel<<<(n4 + 255) / 256, 256, 0, stream>>>(x, Y, n4);
        for (int j = 0; j < 3; ++j) {
            hipMemsetAsync(agg, 0, szY, stream);
            long long threads = (long long)N_EDGES * 16;
            int blocks = (int)((threads + 255) / 256);
            scatter_kernel<<<blocks, 256, 0, stream>>>(Y, src, dst, agg, N_EDGES);
            int mb = (N_NODES + 63) / 64;
            mlp_kernel<<<mb, 256, 0, stream>>>(Y, agg, roundW1[j], roundB1[j],
                                               roundW2[j], roundB2[j], N_NODES);
        }
        hipMemsetAsync(em, 0, szEm, stream);
        readout_kernel<<<128, 256, 0, stream>>>(Y, gid, em, N_NODES);
        cls_kernel<<<1, 256, 0, stream>>>(em, cls_W1, cls_b1, cls_W2, cls_b2, out);
    }
}

// Round 4
// 1227.837 us; speedup vs baseline: 7.2076x; 1.2760x over previous
//
#include <hip/hip_runtime.h>
#include <hip/hip_bf16.h>

#define N_NODES 100000
#define N_EDGES 3200000
#define N_GRAPHS 100
#define DIM 64
#define NCLS 10
#define EPS 0.1f
#define SLOPE 0.01f
#define TILES ((N_NODES + 255) / 256)   // 391

using half8  = __attribute__((ext_vector_type(8))) _Float16;
using half4v = __attribute__((ext_vector_type(4))) _Float16;

__device__ __forceinline__ float lrelu(float v) {
    return v >= 0.f ? v : SLOPE * v;
}

// ======================= CSR build =======================
__global__ void __launch_bounds__(256) hist_kernel(const int* __restrict__ dst,
                                                   int* __restrict__ counts, int E) {
    int i = blockIdx.x * 256 + threadIdx.x;
    if (i < E) atomicAdd(&counts[dst[i]], 1);
}

// hierarchical coalesced scan: tile-reduce -> tile-scan -> tile-expand
__global__ void __launch_bounds__(256) tile_reduce_kernel(const int* __restrict__ counts,
                                                          int* __restrict__ tileSum, int N) {
    int i = blockIdx.x * 256 + threadIdx.x;
    int v = (i < N) ? counts[i] : 0;
    v += __shfl_down(v, 32); v += __shfl_down(v, 16); v += __shfl_down(v, 8);
    v += __shfl_down(v, 4);  v += __shfl_down(v, 2);  v += __shfl_down(v, 1);
    __shared__ int ws[4];
    if ((threadIdx.x & 63) == 0) ws[threadIdx.x >> 6] = v;
    __syncthreads();
    if (threadIdx.x == 0) tileSum[blockIdx.x] = ws[0] + ws[1] + ws[2] + ws[3];
}

__global__ void __launch_bounds__(512) tile_scan_kernel(const int* __restrict__ tileSum,
                                                        int* __restrict__ tileBase,
                                                        int* __restrict__ rowptr, int T) {
    __shared__ int sb[512];
    int t = threadIdx.x;
    int v = (t < T) ? tileSum[t] : 0;
    sb[t] = v;
    __syncthreads();
    for (int off = 1; off < 512; off <<= 1) {
        int u = (t >= off) ? sb[t - off] : 0;
        __syncthreads();
        sb[t] += u;
        __syncthreads();
    }
    if (t < T) tileBase[t] = sb[t] - v;      // exclusive base
    if (t == 511) rowptr[N_NODES] = sb[511]; // total = E
}

__global__ void __launch_bounds__(256) tile_expand_kernel(const int* __restrict__ counts,
                                                          const int* __restrict__ tileBase,
                                                          int* __restrict__ rowptr,
                                                          int* __restrict__ cursor, int N) {
    __shared__ int sb[256];
    int b = blockIdx.x, t = threadIdx.x, i = b * 256 + t;
    int v = (i < N) ? counts[i] : 0;
    sb[t] = v;
    __syncthreads();
    for (int off = 1; off < 256; off <<= 1) {
        int u = (t >= off) ? sb[t - off] : 0;
        __syncthreads();
        sb[t] += u;
        __syncthreads();
    }
    if (i < N) {
        int e = tileBase[b] + sb[t] - v;
        rowptr[i] = e;
        cursor[i] = e;
    }
}

__global__ void __launch_bounds__(256) fill_kernel(const int* __restrict__ src,
                                                   const int* __restrict__ dst,
                                                   int* __restrict__ cursor,
                                                   int* __restrict__ ssrc, int E) {
    int e = blockIdx.x * 256 + threadIdx.x;
    if (e < E) {
        int p = atomicAdd(&cursor[dst[e]], 1);
        ssrc[p] = src[e];
    }
}

// ======================= fp32 -> fp16 conversion =======================
__global__ void __launch_bounds__(256) cvt_kernel(const float* __restrict__ x,
                                                  _Float16* __restrict__ H, int n4) {
    int i = blockIdx.x * 256 + threadIdx.x;
    if (i < n4) {
        float4 v = ((const float4*)x)[i];
        half4v h;
        h[0] = (_Float16)v.x; h[1] = (_Float16)v.y;
        h[2] = (_Float16)v.z; h[3] = (_Float16)v.w;
        ((half4v*)H)[i] = h;
    }
}

// ======================= fused gather + MLP round (fp16 storage) =======
// wave per node. Lane partition: sub = lane>>3 (row slot 0..7), seg = lane&7
// (16B / 8-half feature granule). One VMEM instr gathers 8 rows (1 KB/wave).
__global__ void __launch_bounds__(256) round_f16_kernel(
    const _Float16* __restrict__ Hin, _Float16* __restrict__ Hout,
    const int* __restrict__ rowptr, const int* __restrict__ ssrc,
    const float* __restrict__ W1, const float* __restrict__ b1,
    const float* __restrict__ W2, const float* __restrict__ b2, int N) {
    __shared__ float sW1[DIM * DIM];
    __shared__ float sW2[DIM * DIM];
    __shared__ float sb1[DIM];
    __shared__ float sb2[DIM];
    int tid = threadIdx.x;
    for (int i = tid; i < DIM * DIM; i += 256) { sW1[i] = W1[i]; sW2[i] = W2[i]; }
    if (tid < DIM) { sb1[tid] = b1[tid]; sb2[tid] = b2[tid]; }
    __syncthreads();

    const int wave = tid >> 6, lane = tid & 63;
    const int sub = lane >> 3;   // which of 8 rows this lane helps load
    const int seg = lane & 7;    // which 8-half granule of the row
    const int stride = gridDim.x * 4;

    for (int n = blockIdx.x * 4 + wave; n < N; n += stride) {
        const int beg = rowptr[n], end = rowptr[n + 1];
        float acc[8];
#pragma unroll
        for (int j = 0; j < 8; ++j) acc[j] = 0.f;
        if (sub == 0) {  // self term (1+eps)*H[n]
            half8 v = ((const half8*)(Hin + (size_t)n * DIM))[seg];
#pragma unroll
            for (int j = 0; j < 8; ++j) acc[j] = (1.0f + EPS) * (float)v[j];
        }
        for (int base = beg; base < end; base += 64) {
            int rem = end - base;
            int cnt = rem < 64 ? rem : 64;
            int idx = 0;
            if (lane < cnt) idx = ssrc[base + lane];  // 1 coalesced load / 64 edges
            int iters = (cnt + 7) >> 3;
            for (int i = 0; i < iters; ++i) {
                int r = __shfl(idx, i * 8 + sub);
                if (i * 8 + sub < cnt) {
                    half8 v = ((const half8*)(Hin + (size_t)r * DIM))[seg];
#pragma unroll
                    for (int j = 0; j < 8; ++j) acc[j] += (float)v[j];
                }
            }
        }
        // fold 8 row-slots (lanes differing in bits 3..5)
#pragma unroll
        for (int j = 0; j < 8; ++j) {
            acc[j] += __shfl_xor(acc[j], 8);
            acc[j] += __shfl_xor(acc[j], 16);
            acc[j] += __shfl_xor(acc[j], 32);
        }
        // every lane now holds h[seg*8 + j] (replicated across subs)
        float c1 = sb1[lane];
#pragma unroll
        for (int s = 0; s < 8; ++s)
#pragma unroll
            for (int j = 0; j < 8; ++j)
                c1 += __shfl(acc[j], s) * sW1[(s * 8 + j) * DIM + lane];
        c1 = lrelu(c1);
        float c2 = sb2[lane];
#pragma unroll
        for (int k = 0; k < DIM; ++k) c2 += __shfl(c1, k) * sW2[k * DIM + lane];
        Hout[(size_t)n * DIM + lane] = (_Float16)lrelu(lrelu(c2));
    }
}

// ======================= readout + classifier =======================
__global__ void __launch_bounds__(256) readout_f16_kernel(const _Float16* __restrict__ H,
                                                          const int* __restrict__ gid,
                                                          float* __restrict__ em, int N) {
    __shared__ float sAcc[N_GRAPHS * DIM];
    for (int i = threadIdx.x; i < N_GRAPHS * DIM; i += 256) sAcc[i] = 0.f;
    __syncthreads();
    int lane = threadIdx.x & 63, wave = threadIdx.x >> 6;
    int stride = gridDim.x * 4;
    for (int n = blockIdx.x * 4 + wave; n < N; n += stride) {
        int g = gid[n];
        atomicAdd(&sAcc[g * DIM + lane], (float)H[(size_t)n * DIM + lane]);
    }
    __syncthreads();
    for (int i = threadIdx.x; i < N_GRAPHS * DIM; i += 256) atomicAdd(&em[i], sAcc[i]);
}

__global__ void __launch_bounds__(256) cls_kernel(const float* __restrict__ em,
                                                  const float* __restrict__ W1,
                                                  const float* __restrict__ b1,
                                                  const float* __restrict__ W2,
                                                  const float* __restrict__ b2,
                                                  float* __restrict__ out) {
    __shared__ float sT[N_GRAPHS * DIM];
    __shared__ float sW1[DIM * DIM];
    for (int i = threadIdx.x; i < DIM * DIM; i += 256) sW1[i] = W1[i];
    __syncthreads();
    for (int i = threadIdx.x; i < N_GRAPHS * DIM; i += 256) {
        int g = i >> 6, j = i & 63;
        float acc = b1[j];
#pragma unroll
        for (int k = 0; k < DIM; ++k) acc += em[g * DIM + k] * sW1[k * DIM + j];
        sT[i] = lrelu(acc);
    }
    __syncthreads();
    for (int i = threadIdx.x; i < N_GRAPHS * NCLS; i += 256) {
        int g = i / NCLS, c = i % NCLS;
        float acc = b2[c];
#pragma unroll
        for (int k = 0; k < DIM; ++k) acc += sT[g * DIM + k] * W2[k * NCLS + c];
        out[i] = acc;
    }
}

// ======================= fallback (atomic scatter, fp32) ================
__global__ void copy_kernel(const float* __restrict__ x, float* __restrict__ Y, int n4) {
    int i = blockIdx.x * blockDim.x + threadIdx.x;
    if (i < n4) ((float4*)Y)[i] = ((const float4*)x)[i];
}

__global__ void __launch_bounds__(256) scatter_kernel(const float* __restrict__ Y,
                                                      const int* __restrict__ src,
                                                      const int* __restrict__ dst,
                                                      float* __restrict__ agg, int E) {
    int t = blockIdx.x * blockDim.x + threadIdx.x;
    int e = t >> 4;
    if (e >= E) return;
    int f4 = t & 15;
    int s = src[e];
    int d = dst[e];
    float4 v = ((const float4*)(Y + (size_t)s * DIM))[f4];
    float* ap = agg + (size_t)d * DIM + f4 * 4;
    atomicAdd(ap + 0, v.x);
    atomicAdd(ap + 1, v.y);
    atomicAdd(ap + 2, v.z);
    atomicAdd(ap + 3, v.w);
}

__global__ void __launch_bounds__(256) mlp_kernel(float* __restrict__ Y,
                                                  const float* __restrict__ agg,
                                                  const float* __restrict__ W1,
                                                  const float* __restrict__ b1,
                                                  const float* __restrict__ W2,
                                                  const float* __restrict__ b2, int N) {
    __shared__ float sW1[DIM * DIM];
    __shared__ float sW2[DIM * DIM];
    __shared__ float sb1[DIM];
    __shared__ float sb2[DIM];
    int tid = threadIdx.x;
    for (int i = tid; i < DIM * DIM; i += 256) { sW1[i] = W1[i]; sW2[i] = W2[i]; }
    if (tid < DIM) { sb1[tid] = b1[tid]; sb2[tid] = b2[tid]; }
    __syncthreads();
    int wave = tid >> 6, lane = tid & 63;
    int base = blockIdx.x * 64;
    for (int r = wave; r < 64; r += 4) {
        int row = base + r;
        if (row >= N) break;
        size_t off = (size_t)row * DIM + lane;
        float h = (1.0f + EPS) * Y[off] + agg[off];
        float acc = sb1[lane];
#pragma unroll
        for (int k = 0; k < DIM; ++k) acc += __shfl(h, k) * sW1[k * DIM + lane];
        acc = lrelu(acc);
        float acc2 = sb2[lane];
#pragma unroll
        for (int k = 0; k < DIM; ++k) acc2 += __shfl(acc, k) * sW2[k * DIM + lane];
        Y[off] = lrelu(lrelu(acc2));
    }
}

__global__ void __launch_bounds__(256) readout_kernel(const float* __restrict__ Y,
                                                      const int* __restrict__ gid,
                                                      float* __restrict__ em, int N) {
    __shared__ float sAcc[N_GRAPHS * DIM];
    for (int i = threadIdx.x; i < N_GRAPHS * DIM; i += 256) sAcc[i] = 0.f;
    __syncthreads();
    int lane = threadIdx.x & 63, wave = threadIdx.x >> 6;
    int stride = gridDim.x * 4;
    for (int n = blockIdx.x * 4 + wave; n < N; n += stride) {
        int g = gid[n];
        atomicAdd(&sAcc[g * DIM + lane], Y[(size_t)n * DIM + lane]);
    }
    __syncthreads();
    for (int i = threadIdx.x; i < N_GRAPHS * DIM; i += 256) atomicAdd(&em[i], sAcc[i]);
}

extern "C" void kernel_launch(void* const* d_in, const int* in_sizes, int n_in,
                              void* d_out, int out_size, void* d_ws, size_t ws_size,
                              hipStream_t stream) {
    const float* x       = (const float*)d_in[0];
    const int*   src     = (const int*)d_in[1];
    const int*   dst     = (const int*)d_in[2];
    const int*   gid     = (const int*)d_in[3];
    const float* mlp0_W1 = (const float*)d_in[4];
    const float* mlp0_b1 = (const float*)d_in[5];
    const float* mlp0_W2 = (const float*)d_in[6];
    const float* mlp0_b2 = (const float*)d_in[7];
    const float* mlps_W1 = (const float*)d_in[8];
    const float* mlps_b1 = (const float*)d_in[9];
    const float* mlps_W2 = (const float*)d_in[10];
    const float* mlps_b2 = (const float*)d_in[11];
    const float* cls_W1  = (const float*)d_in[12];
    const float* cls_b1  = (const float*)d_in[13];
    const float* cls_W2  = (const float*)d_in[14];
    const float* cls_b2  = (const float*)d_in[15];
    float* out = (float*)d_out;

    const size_t szH  = (size_t)N_NODES * DIM * sizeof(_Float16);  // 12.8 MB
    const size_t szY  = (size_t)N_NODES * DIM * sizeof(float);     // 25.6 MB
    const size_t szEm = (size_t)N_GRAPHS * DIM * sizeof(float);
    const size_t szRp = (size_t)(N_NODES + 16) * sizeof(int);
    const size_t szN  = (size_t)N_NODES * sizeof(int);
    const size_t szE  = (size_t)N_EDGES * sizeof(int);
    const size_t szT  = 512 * sizeof(int);
    const size_t need = 3 * szH + szEm + szRp + 2 * szN + 2 * szT + szE;  // ~52.6 MB

    const float* roundW1[3] = {mlp0_W1, mlps_W1, mlps_W1 + DIM * DIM};
    const float* roundB1[3] = {mlp0_b1, mlps_b1, mlps_b1 + DIM};
    const float* roundW2[3] = {mlp0_W2, mlps_W2, mlps_W2 + DIM * DIM};
    const float* roundB2[3] = {mlp0_b2, mlps_b2, mlps_b2 + DIM};

    if (ws_size >= need) {
        char* w = (char*)d_ws;
        _Float16* Hx     = (_Float16*)w;  w += szH;
        _Float16* Ha     = (_Float16*)w;  w += szH;
        _Float16* Hb     = (_Float16*)w;  w += szH;
        float*    em     = (float*)w;     w += szEm;
        int*      rowptr = (int*)w;       w += szRp;
        int*      cursor = (int*)w;       w += szN;
        int*      counts = (int*)w;       w += szN;
        int*      tileS  = (int*)w;       w += szT;
        int*      tileB  = (int*)w;       w += szT;
        int*      ssrc   = (int*)w;       w += szE;

        // --- CSR build (coalesced hierarchical scan) ---
        hipMemsetAsync(counts, 0, szN, stream);
        int eBlocks = (N_EDGES + 255) / 256;
        hist_kernel<<<eBlocks, 256, 0, stream>>>(dst, counts, N_EDGES);
        tile_reduce_kernel<<<TILES, 256, 0, stream>>>(counts, tileS, N_NODES);
        tile_scan_kernel<<<1, 512, 0, stream>>>(tileS, tileB, rowptr, TILES);
        tile_expand_kernel<<<TILES, 256, 0, stream>>>(counts, tileB, rowptr, cursor, N_NODES);
        fill_kernel<<<eBlocks, 256, 0, stream>>>(src, dst, cursor, ssrc, N_EDGES);

        // --- x -> fp16 ---
        int n4 = N_NODES * DIM / 4;
        cvt_kernel<<<(n4 + 255) / 256, 256, 0, stream>>>(x, Hx, n4);

        // --- rounds: Hx -> Ha -> Hb -> Ha ---
        const _Float16* Hin[3]  = {Hx, Ha, Hb};
        _Float16*       Hout[3] = {Ha, Hb, Ha};
        for (int j = 0; j < 3; ++j) {
            round_f16_kernel<<<2048, 256, 0, stream>>>(Hin[j], Hout[j], rowptr, ssrc,
                                                       roundW1[j], roundB1[j],
                                                       roundW2[j], roundB2[j], N_NODES);
        }

        hipMemsetAsync(em, 0, szEm, stream);
        readout_f16_kernel<<<128, 256, 0, stream>>>(Ha, gid, em, N_NODES);
        cls_kernel<<<1, 256, 0, stream>>>(em, cls_W1, cls_b1, cls_W2, cls_b2, out);
    } else {
        // fallback: atomic-scatter fp32 path (needs 2*szY + szEm)
        float* Y   = (float*)d_ws;
        float* agg = Y + (size_t)N_NODES * DIM;
        float* em  = agg + (size_t)N_NODES * DIM;
        int n4 = N_NODES * DIM / 4;
        copy_kernel<<<(n4 + 255) / 256, 256, 0, stream>>>(x, Y, n4);
        for (int j = 0; j < 3; ++j) {
            hipMemsetAsync(agg, 0, szY, stream);
            long long threads = (long long)N_EDGES * 16;
            int blocks = (int)((threads + 255) / 256);
            scatter_kernel<<<blocks, 256, 0, stream>>>(Y, src, dst, agg, N_EDGES);
            int mb = (N_NODES + 63) / 64;
            mlp_kernel<<<mb, 256, 0, stream>>>(Y, agg, roundW1[j], roundB1[j],
                                               roundW2[j], roundB2[j], N_NODES);
        }
        hipMemsetAsync(em, 0, szEm, stream);
        readout_kernel<<<128, 256, 0, stream>>>(Y, gid, em, N_NODES);
        cls_kernel<<<1, 256, 0, stream>>>(em, cls_W1, cls_b1, cls_W2, cls_b2, out);
    }
}